// Round 1
// baseline (547.154 us; speedup 1.0000x reference)
//
#include <hip/hip_runtime.h>

// Embedding gather: out[token, :] = W[:, x[token]]
//   x: [B*S] int32 token ids          (in_sizes[0] = 16384)
//   W: [DIMS, TOKENS] float32 row-major (in_sizes[1] = 1024*50257)
//   out: [B*S, DIMS] float32
//
// W's column gather is inherently scattered (stride TOKENS*4 = 201 KB), but
// ~every 128B line of W is needed by >=1 of the 16384 random tokens, so the
// HBM floor is "read all of W once" (~206 MB) + write 64 MB. We make the
// WRITE side perfectly coalesced (float4, contiguous 4KB per token) and let
// L2/LLC absorb the read scatter. One block (256 thr) per token; each thread
// gathers 4 dims and does one float4 store. Token id is block-uniform ->
// scalar load.

#define DIMS   1024
#define TOKENS 50257

__global__ __launch_bounds__(256) void embed_gather_kernel(
    const int* __restrict__ x,
    const float* __restrict__ W,
    float* __restrict__ out,
    int n_tokens)
{
    const int tokidx = blockIdx.x;
    if (tokidx >= n_tokens) return;

    const int t = x[tokidx];                 // block-uniform -> s_load
    const int d0 = threadIdx.x << 2;         // 256 threads * 4 dims = 1024

    const float* __restrict__ col = W + t;   // column base
    float4 v;
    v.x = col[(size_t)(d0 + 0) * TOKENS];
    v.y = col[(size_t)(d0 + 1) * TOKENS];
    v.z = col[(size_t)(d0 + 2) * TOKENS];
    v.w = col[(size_t)(d0 + 3) * TOKENS];

    reinterpret_cast<float4*>(out + (size_t)tokidx * DIMS)[threadIdx.x] = v;
}

extern "C" void kernel_launch(void* const* d_in, const int* in_sizes, int n_in,
                              void* d_out, int out_size, void* d_ws, size_t ws_size,
                              hipStream_t stream) {
    const int*   x = (const int*)d_in[0];     // [B*S] token ids
    const float* W = (const float*)d_in[1];   // [DIMS, TOKENS]
    float*     out = (float*)d_out;           // [B*S, DIMS]

    const int n_tokens = in_sizes[0];         // 16384

    dim3 grid(n_tokens);
    dim3 block(256);                          // 4 dims per thread
    embed_gather_kernel<<<grid, block, 0, stream>>>(x, W, out, n_tokens);
}

// Round 2
// 346.493 us; speedup vs baseline: 1.5791x; 1.5791x over previous
//
#include <hip/hip_runtime.h>

// Embedding gather, inverted: stream W once (coalesced), scatter to out.
//
//   x: [16384] int32 token ids
//   W: [DIMS=1024, TOKENS=50257] float32 row-major (token vec = COLUMN of W)
//   out: [16384, 1024] float32
//
// R0 lesson: per-token column gather fetches 64B/sector per 4B load with zero
// reuse -> 1.05 GB HBM fetch (5x the 206 MB floor). Fix: counting-sort token
// occurrences into 786 windows of 64 consecutive ids, then one block per
// (window, 64-dim chunk) stages the [64 dims x 64 ids] W tile via fully
// coalesced reads into LDS and writes each resident token's 64 dims
// contiguously. Reads = all of W exactly once, streaming.

#define DIMS    1024
#define TOKENS  50257
#define WBITS   6
#define WSIZE   64
#define NW      ((TOKENS + WSIZE - 1) / WSIZE)   // 786 windows

__global__ void zero_cnt(int* cnt) {
    int t = threadIdx.x;
    if (t < NW) cnt[t] = 0;
}

__global__ void hist_kernel(const int* __restrict__ x, int* __restrict__ cnt, int n) {
    int i = blockIdx.x * blockDim.x + threadIdx.x;
    if (i < n) atomicAdd(&cnt[x[i] >> WBITS], 1);
}

// Single-block Hillis-Steele scan over NW=786 bins -> offs (exclusive, +total)
// and cursor (scatter write heads).
__global__ __launch_bounds__(1024) void scan_kernel(const int* __restrict__ cnt,
                                                    int* __restrict__ offs,
                                                    int* __restrict__ cursor) {
    __shared__ int s[1024];
    int t = threadIdx.x;
    int v = (t < NW) ? cnt[t] : 0;
    s[t] = v;
    __syncthreads();
    for (int off = 1; off < 1024; off <<= 1) {
        int u = (t >= off) ? s[t - off] : 0;
        __syncthreads();
        s[t] += u;
        __syncthreads();
    }
    if (t < NW) {
        offs[t + 1] = s[t];        // inclusive prefix
        cursor[t]   = s[t] - v;    // exclusive prefix
    }
    if (t == 0) offs[0] = 0;
}

__global__ void scatter_kernel(const int* __restrict__ x, int* __restrict__ cursor,
                               int* __restrict__ sorted_pos, int* __restrict__ sorted_tok,
                               int n) {
    int i = blockIdx.x * blockDim.x + threadIdx.x;
    if (i < n) {
        int tok = x[i];
        int p = atomicAdd(&cursor[tok >> WBITS], 1);
        sorted_pos[p] = i;
        sorted_tok[p] = tok;
    }
}

// Block (w = blockIdx.x, dchunk = blockIdx.y): stage W[dbase:dbase+64, w*64:(w+1)*64]
// into LDS (coalesced 256B/wave reads), then for each token in window w write
// its 64 dims contiguously to out.
__global__ __launch_bounds__(256) void embed_main(
    const float* __restrict__ W,
    const int* __restrict__ offs,
    const int* __restrict__ sorted_pos,
    const int* __restrict__ sorted_tok,
    float* __restrict__ out)
{
    __shared__ float tile[WSIZE * 65];          // [dim_row][id_col], pad 65: 2-way max (free)
    const int w     = blockIdx.x;
    const int dbase = blockIdx.y * WSIZE;
    const int t  = threadIdx.x;
    const int c  = t & 63;                       // id column within window
    const int rq = t >> 6;                       // 0..3

    const int id0 = w * WSIZE;
    const int id  = id0 + c;
    const bool ok = (id < TOKENS);               // last window is partial

    #pragma unroll
    for (int i = 0; i < 16; ++i) {
        int r = i * 4 + rq;                      // dim row 0..63
        float v = ok ? W[(size_t)(dbase + r) * TOKENS + id] : 0.0f;
        tile[r * 65 + c] = v;
    }
    __syncthreads();

    const int beg = offs[w];
    const int n   = offs[w + 1] - beg;
    const int d  = t & 63;                       // lanes sweep 64 dims -> coalesced store
    const int jo = t >> 6;                       // 4 tokens per iteration
    for (int jb = 0; jb < n; jb += 4) {
        int j = jb + jo;
        if (j < n) {
            int tok = sorted_tok[beg + j];
            int p   = sorted_pos[beg + j];
            float v = tile[d * 65 + (tok - id0)];
            out[(size_t)p * DIMS + dbase + d] = v;
        }
    }
}

extern "C" void kernel_launch(void* const* d_in, const int* in_sizes, int n_in,
                              void* d_out, int out_size, void* d_ws, size_t ws_size,
                              hipStream_t stream) {
    const int*   x = (const int*)d_in[0];     // [16384]
    const float* W = (const float*)d_in[1];   // [1024, 50257]
    float*     out = (float*)d_out;

    const int n = in_sizes[0];                // 16384

    // workspace layout (ints)
    int* cnt        = (int*)d_ws;             // NW
    int* offs       = cnt + NW;               // NW+1
    int* cursor     = offs + (NW + 1);        // NW
    int* sorted_pos = cursor + NW;            // n
    int* sorted_tok = sorted_pos + n;         // n

    zero_cnt<<<1, 1024, 0, stream>>>(cnt);
    hist_kernel<<<(n + 255) / 256, 256, 0, stream>>>(x, cnt, n);
    scan_kernel<<<1, 1024, 0, stream>>>(cnt, offs, cursor);
    scatter_kernel<<<(n + 255) / 256, 256, 0, stream>>>(x, cursor, sorted_pos, sorted_tok, n);

    dim3 grid(NW, DIMS / WSIZE);              // 786 x 16
    embed_main<<<grid, 256, 0, stream>>>(W, offs, sorted_pos, sorted_tok, out);
}